// Round 17
// baseline (1187.868 us; speedup 1.0000x reference)
//
#include <hip/hip_runtime.h>
#include <math.h>

#define N_NODE 50000
#define DD 64
#define NE 800000
#define BB 16
#define LL 50
#define NH 8
#define DK 8
#define NEGV -1e9f
#define NB 49
#define NBLK 256
#define EPB 3125

#define OFF_PDIST 80000000u
#define OFF_FDIST 80320000u
#define OFF_L2P 80640000u
#define OFF_L2F 80691200u

typedef unsigned short ushortt;
typedef __attribute__((ext_vector_type(8))) short bf16x8v;
typedef __attribute__((ext_vector_type(4))) float f32x4v;
typedef __attribute__((ext_vector_type(4))) unsigned int u32x4v;

__device__ __forceinline__ float b2f(ushortt h) { return __uint_as_float(((unsigned)h) << 16); }
__device__ __forceinline__ ushortt f2b(float f) {
    unsigned u = __float_as_uint(f);
    return (ushortt)((u + 0x7fffu + ((u >> 16) & 1u)) >> 16);
}
__device__ __forceinline__ void acc8(float* a, uint4 x) {
    a[0] += b2f((ushortt)(x.x)); a[1] += b2f((ushortt)(x.x >> 16));
    a[2] += b2f((ushortt)(x.y)); a[3] += b2f((ushortt)(x.y >> 16));
    a[4] += b2f((ushortt)(x.z)); a[5] += b2f((ushortt)(x.z >> 16));
    a[6] += b2f((ushortt)(x.w)); a[7] += b2f((ushortt)(x.w >> 16));
}
__device__ __forceinline__ uint4 pack8(const float* a) {
    uint4 w;
    w.x = (unsigned)f2b(a[0]) | ((unsigned)f2b(a[1]) << 16);
    w.y = (unsigned)f2b(a[2]) | ((unsigned)f2b(a[3]) << 16);
    w.z = (unsigned)f2b(a[4]) | ((unsigned)f2b(a[5]) << 16);
    w.w = (unsigned)f2b(a[6]) | ((unsigned)f2b(a[7]) << 16);
    return w;
}
// XCD-class -> (channel, slot). grid.x = 50000 (multiple of 8).
__device__ __forceinline__ bool xcd_map(int bid, int& c, int& slot) {
    int r = bid & 7;
    c = (r * 3) >> 3;
    int nclass = (c == 2) ? 2 : 3;
    int base = (c == 0) ? 0 : ((c == 1) ? 3 : 6);
    slot = (bid >> 3) * nclass + (r - base);
    return slot < 12500;
}

// ---------------- zero fill ----------------
__global__ void k_zero(float* p, int n) {
    int i = blockIdx.x * 256 + threadIdx.x;
    if (i < n) p[i] = 0.0f;
}

// ================= CSR build =================
__global__ __launch_bounds__(256) void k_cnt(const int* __restrict__ eg,
                                             const int* __restrict__ ei,
                                             const int* __restrict__ eu,
                                             int* __restrict__ hist) {
    int c = blockIdx.y;
    const int* ed = (c == 0) ? eg : ((c == 1) ? ei : eu);
    int blk = blockIdx.x;
    __shared__ int lc[2 * NB];
    int tid = threadIdx.x;
    for (int j = tid; j < 2 * NB; j += 256) lc[j] = 0;
    __syncthreads();
    int e0 = blk * EPB;
    for (int i = e0 + tid; i < e0 + EPB; i += 256) {
        atomicAdd(&lc[ed[NE + i] >> 10], 1);
        atomicAdd(&lc[NB + (ed[i] >> 10)], 1);
    }
    __syncthreads();
    for (int j = tid; j < 2 * NB; j += 256) {
        int side = (j >= NB);
        int b = side ? (j - NB) : j;
        hist[(((side * 3 + c) * NB) + b) * NBLK + blk] = lc[j];
    }
}

__global__ __launch_bounds__(256) void k_scanH(int* __restrict__ hist, int* __restrict__ bb) {
    int t6 = blockIdx.x;
    int* h = hist + t6 * NB * NBLK;
    __shared__ int part[256];
    int tid = threadIdx.x;
    const int CH = (NB * NBLK) / 256;
    int base = tid * CH;
    int s = 0;
    for (int i = 0; i < CH; i++) s += h[base + i];
    part[tid] = s;
    __syncthreads();
    for (int o = 1; o < 256; o <<= 1) {
        int v = (tid >= o) ? part[tid - o] : 0;
        __syncthreads();
        part[tid] += v;
        __syncthreads();
    }
    int run = (tid == 0) ? 0 : part[tid - 1];
    for (int i = 0; i < CH; i++) {
        int idx = base + i;
        int v = h[idx];
        if ((idx & (NBLK - 1)) == 0) bb[t6 * (NB + 1) + (idx >> 8)] = run;
        h[idx] = run;
        run += v;
    }
    if (tid == 255) bb[t6 * (NB + 1) + NB] = run;
}

__global__ __launch_bounds__(256) void k_part2(const int* __restrict__ eg,
                                               const int* __restrict__ ei,
                                               const int* __restrict__ eu,
                                               const int* __restrict__ hist,
                                               unsigned* __restrict__ poolB,
                                               unsigned* __restrict__ poolD) {
    int c = blockIdx.y;
    const int* ed = (c == 0) ? eg : ((c == 1) ? ei : eu);
    int blk = blockIdx.x;
    __shared__ int curB[NB], curD[NB];
    int tid = threadIdx.x;
    for (int j = tid; j < NB; j += 256) {
        curB[j] = hist[(((0 * 3 + c) * NB) + j) * NBLK + blk];
        curD[j] = hist[(((1 * 3 + c) * NB) + j) * NBLK + blk];
    }
    __syncthreads();
    unsigned* pB = poolB + c * 800000;
    unsigned* pD = poolD + c * 800000;
    int e0 = blk * EPB;
    for (int i = e0 + tid; i < e0 + EPB; i += 256) {
        int n = ed[i], h = ed[NE + i];
        int pb = atomicAdd(&curB[h >> 10], 1);
        pB[pb] = ((unsigned)h << 16) | (unsigned)n;
        int pd = atomicAdd(&curD[n >> 10], 1);
        pD[pd] = ((unsigned)n << 16) | (unsigned)h;
    }
}

__global__ __launch_bounds__(256) void k_bucket(const unsigned* __restrict__ poolB,
                                                const unsigned* __restrict__ poolD,
                                                const int* __restrict__ bb,
                                                int* __restrict__ nbrB3, int* __restrict__ nbrD3,
                                                int* __restrict__ offB3, int* __restrict__ offD3,
                                                float* __restrict__ invB3, float* __restrict__ invD3) {
    int b = blockIdx.x, c = blockIdx.y, side = blockIdx.z;
    const unsigned* pool = (side ? poolD : poolB) + c * 800000;
    int* nbr = (side ? nbrD3 : nbrB3) + c * 800000;
    int* off = (side ? offD3 : offB3) + c * 50001;
    float* inv = (side ? invD3 : invB3) + c * 50000;
    int t6 = side * 3 + c;
    int s0 = bb[t6 * (NB + 1) + b], s1 = bb[t6 * (NB + 1) + b + 1];
    int baseSeg = b << 10;
    __shared__ int cnt[1024];
    __shared__ int ofs[1024];
    __shared__ int part[256];
    int tid = threadIdx.x;
    for (int j = tid; j < 1024; j += 256) cnt[j] = 0;
    __syncthreads();
    for (int i = s0 + tid; i < s1; i += 256)
        atomicAdd(&cnt[(pool[i] >> 16) & 1023], 1);
    __syncthreads();
    int t4 = tid * 4;
    int a0 = cnt[t4], a1 = cnt[t4 + 1], a2 = cnt[t4 + 2], a3 = cnt[t4 + 3];
    part[tid] = a0 + a1 + a2 + a3;
    __syncthreads();
    for (int o = 1; o < 256; o <<= 1) {
        int v = (tid >= o) ? part[tid - o] : 0;
        __syncthreads();
        part[tid] += v;
        __syncthreads();
    }
    int excl = (tid == 0) ? 0 : part[tid - 1];
    ofs[t4] = excl;
    ofs[t4 + 1] = excl + a0;
    ofs[t4 + 2] = excl + a0 + a1;
    ofs[t4 + 3] = excl + a0 + a1 + a2;
    __syncthreads();
    for (int ls = tid; ls < 1024; ls += 256) {
        int seg = baseSeg + ls;
        if (seg < N_NODE) {
            off[seg] = s0 + ofs[ls];
            inv[seg] = cnt[ls] ? 1.0f / (float)cnt[ls] : 0.0f;
        }
    }
    if (b == NB - 1 && tid == 0) off[N_NODE] = NE;
    __syncthreads();
    for (int i = s0 + tid; i < s1; i += 256) {
        unsigned u = pool[i];
        int ls = (u >> 16) & 1023;
        int p = atomicAdd(&ofs[ls], 1);
        nbr[s0 + p] = (int)(u & 0xFFFFu);
    }
}

// ---------------- fused gate ----------------
__global__ __launch_bounds__(256) void k_gateX(const float* __restrict__ emb,
                                               const float* __restrict__ gate_w,
                                               const float* __restrict__ gate_b,
                                               float* __restrict__ acc3,
                                               ushortt* __restrict__ xt3) {
    int c = blockIdx.y;
    const float* W = gate_w + c * 4096;
    const float* bias = gate_b + c * 64;
    float* acc = acc3 + (size_t)c * 3200000;
    ushortt* xt = xt3 + (size_t)c * 3200000;
    __shared__ float sW[64 * 64];
    __shared__ float sx[4][64];
    int tid = threadIdx.x;
    for (int i = tid; i < 4096; i += 256) sW[i] = W[i];
    int r = tid >> 6;
    int d = tid & 63;
    int n = blockIdx.x * 4 + r;
    sx[r][d] = emb[n * DD + d];
    __syncthreads();
    float a = bias[d];
#pragma unroll
    for (int k = 0; k < 64; k++) a += sx[r][k] * sW[k * 64 + d];
    float x = sx[r][d] * (1.0f / (1.0f + expf(-a)));
    acc[n * DD + d] = x;
    xt[n * DD + d] = f2b(x);
}

// ---------------- half-row gather: dst[seg][h*32..] = inv*sum src[nbr][h*32..] ----------------
__global__ __launch_bounds__(256) void k_gathH(const ushortt* __restrict__ srcb,
                                               const int* __restrict__ off3,
                                               const int* __restrict__ nbr3,
                                               const float* __restrict__ inv3,
                                               ushortt* __restrict__ dstb,
                                               int half) {
    int c, slot;
    if (!xcd_map(blockIdx.x, c, slot)) return;
    const ushortt* src = srcb + (size_t)c * 3200000 + half * 32;
    ushortt* dst = dstb + (size_t)c * 3200000 + half * 32;
    const int* off = off3 + c * 50001;
    const int* nbr = nbr3 + c * 800000;
    const float* inv = inv3 + c * 50000;
    int seg = slot * 4 + (threadIdx.x >> 6);
    int lane = threadIdx.x & 63;
    int sub = lane >> 2;   // 16 entry slots
    int c4 = lane & 3;     // 16B chunk within 64B half-row
    int s = off[seg], e = off[seg + 1];
    float a[8] = {0.f, 0.f, 0.f, 0.f, 0.f, 0.f, 0.f, 0.f};
    int i = s + sub;
    if (i < e) {
        int nb = __builtin_nontemporal_load(&nbr[i]);
        uint4 x = ((const uint4*)(src + (size_t)nb * DD))[c4];
        for (i += 16; i < e; i += 16) {
            int nb2 = __builtin_nontemporal_load(&nbr[i]);
            uint4 nx = ((const uint4*)(src + (size_t)nb2 * DD))[c4];
            acc8(a, x);
            x = nx;
        }
        acc8(a, x);
    }
#pragma unroll
    for (int j = 0; j < 8; j++) {
        a[j] += __shfl_xor(a[j], 4, 64);
        a[j] += __shfl_xor(a[j], 8, 64);
        a[j] += __shfl_xor(a[j], 16, 64);
        a[j] += __shfl_xor(a[j], 32, 64);
    }
    if (sub == 0) {
        float sc = inv[seg];
        float b[8];
#pragma unroll
        for (int j = 0; j < 8; j++) b[j] = a[j] * sc;
        u32x4v w;
        w.x = (unsigned)f2b(b[0]) | ((unsigned)f2b(b[1]) << 16);
        w.y = (unsigned)f2b(b[2]) | ((unsigned)f2b(b[3]) << 16);
        w.z = (unsigned)f2b(b[4]) | ((unsigned)f2b(b[5]) << 16);
        w.w = (unsigned)f2b(b[6]) | ((unsigned)f2b(b[7]) << 16);
        __builtin_nontemporal_store(w, (u32x4v*)(dst + (size_t)seg * DD) + c4);
    }
}

// ---------------- theta pass: v = t@theta + bias; acc += v/||v||; t <- bf16(v) ----------------
template <int WRITE_XT>
__global__ __launch_bounds__(256) void k_theta(ushortt* __restrict__ t3,
                                               const float* __restrict__ theta,
                                               const float* __restrict__ theta_b,
                                               float* __restrict__ acc3) {
    int c = blockIdx.y;
    ushortt* t = t3 + (size_t)c * 3200000;
    float* acc = acc3 + (size_t)c * 3200000;
    __shared__ float sTh[4096];
    __shared__ float sx[4][64];
    __shared__ float sb[64];
    int tid = threadIdx.x;
    for (int i = tid; i < 4096; i += 256) sTh[i] = theta[i];
    if (tid < 64) sb[tid] = theta_b[tid];
    int r = tid >> 6, d = tid & 63;
    int n = blockIdx.x * 4 + r;
    sx[r][d] = b2f(t[(size_t)n * DD + d]);
    __syncthreads();
    float v = sb[d];
#pragma unroll
    for (int k = 0; k < 64; k++) v += sx[r][k] * sTh[k * 64 + d];
    float ss = v * v;
#pragma unroll
    for (int o = 32; o; o >>= 1) ss += __shfl_xor(ss, o, 64);
    float nr = fmaxf(sqrtf(ss), 1e-12f);
    size_t idx = (size_t)n * DD + d;
    acc[idx] += v / nr;
    if (WRITE_XT) t[idx] = f2b(v);
}

// ---------------- channel softmax combine -> HG (fp32 + bf16) ----------------
__global__ __launch_bounds__(256) void k_comb(const float* __restrict__ a0,
                                              const float* __restrict__ a1,
                                              const float* __restrict__ a2,
                                              const float* __restrict__ att_m,
                                              const float* __restrict__ att,
                                              float* __restrict__ HG,
                                              ushortt* __restrict__ HG16) {
    __shared__ float svv[64];
    int tid = threadIdx.x;
    if (tid < 64) {
        float s = 0.f;
        for (int k = 0; k < 64; k++) s += att_m[tid * 64 + k] * att[k];
        svv[tid] = s;
    }
    __syncthreads();
    int r = tid >> 6;
    int d = tid & 63;
    int n = blockIdx.x * 4 + r;
    float x0 = a0[n * DD + d], x1 = a1[n * DD + d], x2 = a2[n * DD + d];
    float vd = svv[d];
    float l0 = x0 * vd, l1 = x1 * vd, l2 = x2 * vd;
#pragma unroll
    for (int o = 32; o; o >>= 1) {
        l0 += __shfl_xor(l0, o, 64);
        l1 += __shfl_xor(l1, o, 64);
        l2 += __shfl_xor(l2, o, 64);
    }
    l0 *= (1.0f / 3.0f); l1 *= (1.0f / 3.0f); l2 *= (1.0f / 3.0f);
    float mx = fmaxf(l0, fmaxf(l1, l2));
    float e0 = expf(l0 - mx), e1 = expf(l1 - mx), e2 = expf(l2 - mx);
    float inv = 1.0f / (e0 + e1 + e2);
    float hv = (e0 * x0 + e1 * x1 + e2 * x2) * inv * (1.0f / 3.0f);
    HG[n * DD + d] = hv;
    HG16[n * DD + d] = f2b(hv);
}

// ---------------- attention per head ----------------
__global__ __launch_bounds__(256) void k_attnh(const float* __restrict__ HG,
                                               const int* __restrict__ iseq,
                                               const int* __restrict__ lseq,
                                               const float* __restrict__ w_hist,
                                               const float* __restrict__ w_fut,
                                               float* __restrict__ dout,
                                               float* __restrict__ hout) {
    int b = blockIdx.x, h = blockIdx.y, dir = blockIdx.z;
    const int* seq = dir ? lseq : iseq;
    const float* W = dir ? w_fut : w_hist;
    float* dist = dout + (dir ? OFF_FDIST : OFF_PDIST);
    __shared__ float sX[LL * 64];
    __shared__ float sQ[LL * DK], sK[LL * DK], sV[LL * DK];
    __shared__ float sS[LL * LL];
    __shared__ int sseq[LL];
    int tid = threadIdx.x, w = tid >> 6, lane = tid & 63;
    if (tid < LL) sseq[tid] = seq[b * LL + tid];
    __syncthreads();
    for (int idx = tid; idx < LL * 64; idx += 256)
        sX[idx] = HG[sseq[idx >> 6] * DD + (idx & 63)];
    __syncthreads();
    for (int idx = tid; idx < LL * DK; idx += 256) {
        int i = idx / DK, d = idx % DK;
        int col = h * 8 + d;
        float q = 0, k = 0, v = 0;
        for (int kk = 0; kk < 64; kk++) {
            float x = sX[i * 64 + kk];
            q += x * W[kk * 64 + col];
            k += x * W[4096 + kk * 64 + col];
            v += x * W[8192 + kk * 64 + col];
        }
        sQ[idx] = q; sK[idx] = k; sV[idx] = v;
    }
    __syncthreads();
    const float scale = 0.35355339059327373f;
    for (int idx = tid; idx < LL * LL; idx += 256) {
        int i = idx / LL, j = idx % LL;
        float s = 0;
#pragma unroll
        for (int d = 0; d < DK; d++) s += sQ[i * DK + d] * sK[j * DK + d];
        s *= scale;
        bool allowed = dir ? (j >= i) : (j <= i);
        if (!allowed || sseq[j] == 0) s = NEGV;
        sS[idx] = s;
    }
    __syncthreads();
    for (int i = w; i < LL; i += 4) {
        float v = (lane < LL) ? sS[i * LL + lane] : -INFINITY;
        float mx = v;
#pragma unroll
        for (int o = 32; o; o >>= 1) mx = fmaxf(mx, __shfl_xor(mx, o, 64));
        float e = (lane < LL) ? expf(v - mx) : 0.0f;
        float sum = e;
#pragma unroll
        for (int o = 32; o; o >>= 1) sum += __shfl_xor(sum, o, 64);
        float p = e / sum;
        if (lane < LL) {
            sS[i * LL + lane] = p;
            dist[((b * NH + h) * LL + i) * LL + lane] = p;
        }
    }
    __syncthreads();
    for (int idx = tid; idx < LL * DK; idx += 256) {
        int i = idx / DK, d = idx % DK;
        float o = 0;
        for (int j = 0; j < LL; j++) o += sS[i * LL + j] * sV[j * DK + d];
        hout[((size_t)(dir * 800 + b * LL + i)) * 64 + h * 8 + d] = o;
    }
}

// ---------------- attention out-projection + A16 + fused l2 ----------------
__global__ __launch_bounds__(256) void k_attno(const float* __restrict__ hout,
                                               const float* __restrict__ w_hist,
                                               const float* __restrict__ w_fut,
                                               float* __restrict__ dout,
                                               ushortt* __restrict__ attout16) {
    int b = blockIdx.x, dir = blockIdx.y;
    const float* W = dir ? w_fut : w_hist;
    __shared__ float sH[LL * 64];
    __shared__ float sO[LL * 64];
    __shared__ float sInv[64];
    int tid = threadIdx.x;
    for (int idx = tid; idx < LL * 64; idx += 256)
        sH[idx] = hout[((size_t)(dir * 800 + b * LL)) * 64 + idx];
    __syncthreads();
    for (int idx = tid; idx < LL * 64; idx += 256) {
        int i = idx >> 6, d = idx & 63;
        float o = 0;
        for (int kk = 0; kk < 64; kk++) o += sH[i * 64 + kk] * W[3 * 4096 + kk * 64 + d];
        sO[idx] = o;
        int row = dir * 800 + b * LL + i;
        attout16[row * 64 + d] = f2b(o);
    }
    __syncthreads();
    if (tid < 64) {
        float s = 0;
        for (int l = 0; l < LL; l++) {
            float x = sO[l * 64 + tid];
            s += x * x;
        }
        sInv[tid] = 1.0f / fmaxf(sqrtf(s), 1e-12f);
    }
    __syncthreads();
    float* ol2 = dout + (dir ? OFF_L2F : OFF_L2P) + b * LL * 64;
    for (int idx = tid; idx < LL * 64; idx += 256) ol2[idx] = sO[idx] * sInv[idx & 63];
}

// ---------------- big matmul via MFMA; LDS-transposed nt stores ----------------
__global__ __launch_bounds__(256) void k_bigmm_mfma(const ushortt* __restrict__ A16,
                                                    const ushortt* __restrict__ HG16,
                                                    float* __restrict__ out) {
    __shared__ float sO[16][260];
    int tid = threadIdx.x;
    int lane = tid & 63;
    int w = tid >> 6;
    int rt = blockIdx.y;
    int colBase = blockIdx.x * 256;
    int lrow = lane & 15;
    int kb = (lane >> 4) * 8;
    int arow = rt * 16 + lrow;
    bf16x8v a0 = *(const bf16x8v*)(A16 + (size_t)arow * 64 + kb);
    bf16x8v a1 = *(const bf16x8v*)(A16 + (size_t)arow * 64 + kb + 32);
#pragma unroll
    for (int ct = 0; ct < 4; ct++) {
        int lc = w * 64 + ct * 16 + lrow;
        int col = colBase + lc;
        int colc = (col < N_NODE) ? col : 0;
        bf16x8v b0 = *(const bf16x8v*)(HG16 + (size_t)colc * 64 + kb);
        bf16x8v b1 = *(const bf16x8v*)(HG16 + (size_t)colc * 64 + kb + 32);
        f32x4v acc = {0.f, 0.f, 0.f, 0.f};
        acc = __builtin_amdgcn_mfma_f32_16x16x32_bf16(a0, b0, acc, 0, 0, 0);
        acc = __builtin_amdgcn_mfma_f32_16x16x32_bf16(a1, b1, acc, 0, 0, 0);
        int r0 = (lane >> 4) * 4;
#pragma unroll
        for (int j = 0; j < 4; j++) sO[r0 + j][lc] = acc[j];
    }
    __syncthreads();
#pragma unroll
    for (int j = 0; j < 4; j++) {
        int r = w * 4 + j;
        int row = rt * 16 + r;
        int c0 = colBase + lane * 4;
        f32x4v v = {sO[r][lane * 4], sO[r][lane * 4 + 1],
                    sO[r][lane * 4 + 2], sO[r][lane * 4 + 3]};
        if (c0 + 3 < N_NODE) {
            __builtin_nontemporal_store(v, (f32x4v*)(out + (size_t)row * 50000 + c0));
        } else {
            for (int t = 0; t < 4; t++)
                if (c0 + t < N_NODE) out[(size_t)row * 50000 + c0 + t] = v[t];
        }
    }
}

// ---------------- prev-user mask ----------------
__global__ __launch_bounds__(64) void k_mask(const int* __restrict__ iseq,
                                             float* __restrict__ out) {
    int row = blockIdx.x;
    int b = row / LL, i = row % LL;
    __shared__ int s[LL];
    int tid = threadIdx.x;
    if (tid < LL) s[tid] = iseq[b * LL + tid];
    __syncthreads();
    float* o = out + (size_t)row * 50000;
    if (tid == 0) o[0] -= 1000.0f;
    if (tid < LL && tid <= i) {
        int c = s[tid];
        if (c > 0 && c < N_NODE) {
            bool first = true;
            for (int j = 0; j < tid; j++)
                if (s[j] == c) { first = false; break; }
            if (first) o[c] -= 1000.0f;
        }
    }
}

// ================= fallback atomic path kernels =================
__global__ void k_deg(const int* __restrict__ node, const int* __restrict__ hedge,
                      float* __restrict__ Ddeg, float* __restrict__ Bdeg) {
    int e = blockIdx.x * 256 + threadIdx.x;
    if (e < NE) {
        atomicAdd(&Ddeg[node[e]], 1.0f);
        atomicAdd(&Bdeg[hedge[e]], 1.0f);
    }
}

__global__ void k_inv(float* a, int n) {
    int i = blockIdx.x * 256 + threadIdx.x;
    if (i < n) a[i] = (a[i] > 0.0f) ? (1.0f / a[i]) : 0.0f;
}

__global__ __launch_bounds__(256) void k_scat(const float* __restrict__ src,
                                              const int* __restrict__ gidx,
                                              const int* __restrict__ sidx,
                                              const float* __restrict__ scale,
                                              float* __restrict__ dst) {
    int e = blockIdx.x * 4 + (threadIdx.x >> 6);
    int d = threadIdx.x & 63;
    if (e >= NE) return;
    int g = gidx[e];
    int s = sidx[e];
    float v = src[g * DD + d];
    if (scale) v *= scale[g];
    atomicAdd(&dst[s * DD + d], v);
}

__global__ __launch_bounds__(256) void k_fin(float* __restrict__ cur,
                                             const float* __restrict__ invD,
                                             const float* __restrict__ bias,
                                             float* __restrict__ acc) {
    int r = threadIdx.x >> 6;
    int d = threadIdx.x & 63;
    int n = blockIdx.x * 4 + r;
    float v = cur[n * DD + d] * invD[n] + bias[d];
    cur[n * DD + d] = v;
    float s = v * v;
#pragma unroll
    for (int o = 32; o; o >>= 1) s += __shfl_xor(s, o, 64);
    float nr = fmaxf(sqrtf(s), 1e-12f);
    acc[n * DD + d] += v / nr;
}

__global__ __launch_bounds__(256) void k_gate(const float* __restrict__ emb,
                                              const float* __restrict__ W,
                                              const float* __restrict__ bias,
                                              float* __restrict__ cur,
                                              float* __restrict__ acc) {
    __shared__ float sW[64 * 64];
    __shared__ float sx[4][64];
    int tid = threadIdx.x;
    for (int i = tid; i < 4096; i += 256) sW[i] = W[i];
    int r = tid >> 6;
    int d = tid & 63;
    int n = blockIdx.x * 4 + r;
    sx[r][d] = emb[n * DD + d];
    __syncthreads();
    float a = bias[d];
#pragma unroll
    for (int k = 0; k < 64; k++) a += sx[r][k] * sW[k * 64 + d];
    float x = sx[r][d] * (1.0f / (1.0f + expf(-a)));
    cur[n * DD + d] = x;
    acc[n * DD + d] = x;
}

__global__ __launch_bounds__(256) void k_mm64(const float* __restrict__ X,
                                              const float* __restrict__ W,
                                              float* __restrict__ Y) {
    __shared__ float sW[64 * 64];
    __shared__ float sx[4][64];
    int tid = threadIdx.x;
    for (int i = tid; i < 4096; i += 256) sW[i] = W[i];
    int r = tid >> 6;
    int d = tid & 63;
    int n = blockIdx.x * 4 + r;
    sx[r][d] = X[n * DD + d];
    __syncthreads();
    float a = 0.0f;
#pragma unroll
    for (int k = 0; k < 64; k++) a += sx[r][k] * sW[k * 64 + d];
    Y[n * DD + d] = a;
}

__global__ __launch_bounds__(256) void k_attnF(const float* __restrict__ HG,
                                               const int* __restrict__ iseq,
                                               const int* __restrict__ lseq,
                                               const float* __restrict__ w_hist,
                                               const float* __restrict__ w_fut,
                                               float* __restrict__ dout,
                                               float* __restrict__ attoutF) {
    int b = blockIdx.x;
    int dir = blockIdx.y;
    const int* seq = (dir == 0) ? iseq : lseq;
    const float* W = (dir == 0) ? w_hist : w_fut;
    float* dist = dout + ((dir == 0) ? OFF_PDIST : OFF_FDIST);
    __shared__ float sX[LL * 64];
    __shared__ float sQ[LL * 64];
    __shared__ float sK[LL * 64];
    __shared__ float sV[LL * 64];
    __shared__ float sS[LL * LL];
    __shared__ float sInv[64];
    __shared__ int sseq[LL];
    int tid = threadIdx.x;
    int w = tid >> 6, lane = tid & 63;
    if (tid < LL) sseq[tid] = seq[b * LL + tid];
    __syncthreads();
    for (int idx = tid; idx < LL * 64; idx += 256) {
        int i = idx >> 6, d = idx & 63;
        sX[idx] = HG[sseq[i] * DD + d];
    }
    __syncthreads();
    for (int idx = tid; idx < LL * 64; idx += 256) {
        int i = idx >> 6, d = idx & 63;
        float q = 0, k = 0, v = 0;
        for (int kk = 0; kk < 64; kk++) {
            float x = sX[i * 64 + kk];
            q += x * W[kk * 64 + d];
            k += x * W[4096 + kk * 64 + d];
            v += x * W[8192 + kk * 64 + d];
        }
        sQ[idx] = q; sK[idx] = k; sV[idx] = v;
    }
    __syncthreads();
    for (int idx = tid; idx < LL * 64; idx += 256) sX[idx] = 0.0f;
    __syncthreads();
    const float scale = 0.35355339059327373f;
    for (int h = 0; h < NH; h++) {
        for (int idx = tid; idx < LL * LL; idx += 256) {
            int i = idx / LL, j = idx % LL;
            float s = 0;
#pragma unroll
            for (int d = 0; d < DK; d++) s += sQ[i * 64 + h * 8 + d] * sK[j * 64 + h * 8 + d];
            s *= scale;
            bool allowed = (dir == 0) ? (j <= i) : (j >= i);
            if (!allowed || sseq[j] == 0) s = NEGV;
            sS[idx] = s;
        }
        __syncthreads();
        for (int i = w; i < LL; i += 4) {
            float v = (lane < LL) ? sS[i * LL + lane] : -INFINITY;
            float mx = v;
#pragma unroll
            for (int o = 32; o; o >>= 1) mx = fmaxf(mx, __shfl_xor(mx, o, 64));
            float e = (lane < LL) ? expf(v - mx) : 0.0f;
            float sum = e;
#pragma unroll
            for (int o = 32; o; o >>= 1) sum += __shfl_xor(sum, o, 64);
            float p = e / sum;
            if (lane < LL) {
                sS[i * LL + lane] = p;
                dist[((b * NH + h) * LL + i) * LL + lane] = p;
            }
        }
        __syncthreads();
        for (int idx = tid; idx < LL * DK; idx += 256) {
            int i = idx / DK, d8 = idx % DK;
            float o = 0;
            for (int j = 0; j < LL; j++) o += sS[i * LL + j] * sV[j * 64 + h * 8 + d8];
            sX[i * 64 + h * 8 + d8] = o;
        }
        __syncthreads();
    }
    for (int idx = tid; idx < LL * 64; idx += 256) {
        int i = idx >> 6, d = idx & 63;
        float o = 0;
        for (int kk = 0; kk < 64; kk++) o += sX[i * 64 + kk] * W[3 * 4096 + kk * 64 + d];
        sQ[idx] = o;
        attoutF[(dir * 800 + b * LL + i) * 64 + d] = o;
    }
    __syncthreads();
    if (tid < 64) {
        float s = 0;
        for (int l = 0; l < LL; l++) {
            float x = sQ[l * 64 + tid];
            s += x * x;
        }
        sInv[tid] = 1.0f / fmaxf(sqrtf(s), 1e-12f);
    }
    __syncthreads();
    float* ol2 = dout + ((dir == 0) ? OFF_L2P : OFF_L2F) + b * LL * 64;
    for (int idx = tid; idx < LL * 64; idx += 256) {
        int d = idx & 63;
        ol2[idx] = sQ[idx] * sInv[d];
    }
}

__global__ __launch_bounds__(256) void k_bigmm5(const float* __restrict__ A,
                                                const float* __restrict__ HG,
                                                float* __restrict__ out) {
    int col = blockIdx.x * 256 + threadIdx.x;
    int r0 = blockIdx.y * 400;
    bool ok = (col < N_NODE);
    float4 h[16];
    const float4* hp = (const float4*)(HG + (size_t)(ok ? col : 0) * 64);
#pragma unroll
    for (int t = 0; t < 16; t++) h[t] = hp[t];
    if (!ok) return;
    for (int r = 0; r < 400; r++) {
        int row = r0 + r;
        const float* ar = A + (size_t)row * 64;
        float q0 = 0.f, q1 = 0.f, q2 = 0.f, q3 = 0.f;
#pragma unroll
        for (int t = 0; t < 16; t++) {
            q0 += ar[4 * t + 0] * h[t].x;
            q1 += ar[4 * t + 1] * h[t].y;
            q2 += ar[4 * t + 2] * h[t].z;
            q3 += ar[4 * t + 3] * h[t].w;
        }
        out[(size_t)row * 50000 + col] = (q0 + q1) + (q2 + q3);
    }
}

extern "C" void kernel_launch(void* const* d_in, const int* in_sizes, int n_in,
                              void* d_out, int out_size, void* d_ws, size_t ws_size,
                              hipStream_t stream) {
    const int* input_seq = (const int*)d_in[0];
    const int* label_seq = (const int*)d_in[1];
    const int* eg = (const int*)d_in[4];
    const int* ei = (const int*)d_in[5];
    const int* eu = (const int*)d_in[6];
    const float* emb = (const float*)d_in[7];
    const float* gate_w = (const float*)d_in[8];
    const float* gate_b = (const float*)d_in[9];
    const float* att = (const float*)d_in[10];
    const float* att_m = (const float*)d_in[11];
    const float* theta = (const float*)d_in[12];
    const float* theta_b = (const float*)d_in[13];
    const float* w_hist = (const float*)d_in[14];
    const float* w_fut = (const float*)d_in[15];

    float* out = (float*)d_out;
    float* ws = (float*)d_ws;

    const size_t HGF = 3200000;
    const int HISTN = 6 * NB * NBLK;
    const size_t needA = (HGF + 150000 + 150000 +
                          (size_t)(HISTN + 6 * (NB + 1) + 64) +
                          300006 + 4 * 2400000 +
                          2 * 2400000 +
                          3 * HGF +
                          HGF / 2 + 51200 + 102400 + 1024) * 4;

    if (ws_size >= needA) {
        size_t o = 0;
        float* HG = ws + o; o += HGF;
        float* invB3 = ws + o; o += 150000;
        float* invD3 = ws + o; o += 150000;
        int* hist = (int*)(ws + o); o += HISTN;
        int* bbarr = (int*)(ws + o); o += 6 * (NB + 1) + 64;
        int* offB3 = (int*)(ws + o); o += 150003;
        int* offD3 = (int*)(ws + o); o += 150003 + 2;
        int* nbrB3 = (int*)(ws + o); o += 2400000;
        int* nbrD3 = (int*)(ws + o); o += 2400000;
        unsigned* poolB = (unsigned*)(ws + o); o += 2400000;
        unsigned* poolD = (unsigned*)(ws + o); o += 2400000;
        ushortt* xt3 = (ushortt*)(ws + o); o += 4800000;
        ushortt* m3 = (ushortt*)(ws + o); o += 4800000;
        float* acc3 = ws + o; o += 3 * HGF;
        ushortt* HG16 = (ushortt*)(ws + o); o += HGF / 2;
        ushortt* A16 = (ushortt*)(ws + o); o += 51200;
        float* hout = ws + o; o += 102400;

        // CSR build
        dim3 pg(NBLK, 3);
        k_cnt<<<pg, 256, 0, stream>>>(eg, ei, eu, hist);
        k_scanH<<<6, 256, 0, stream>>>(hist, bbarr);
        k_part2<<<pg, 256, 0, stream>>>(eg, ei, eu, hist, poolB, poolD);
        dim3 dg(NB, 3, 2);
        k_bucket<<<dg, 256, 0, stream>>>(poolB, poolD, bbarr, nbrB3, nbrD3,
                                         offB3, offD3, invB3, invD3);

        // HG pipeline: gate -> [B half-gathers -> D half-gathers -> theta] x2 -> comb
        dim3 ng3(12500, 3);
        k_gateX<<<ng3, 256, 0, stream>>>(emb, gate_w, gate_b, acc3, xt3);
        for (int k = 0; k < 2; k++) {
            k_gathH<<<50000, 256, 0, stream>>>(xt3, offB3, nbrB3, invB3, m3, 0);
            k_gathH<<<50000, 256, 0, stream>>>(xt3, offB3, nbrB3, invB3, m3, 1);
            k_gathH<<<50000, 256, 0, stream>>>(m3, offD3, nbrD3, invD3, xt3, 0);
            k_gathH<<<50000, 256, 0, stream>>>(m3, offD3, nbrD3, invD3, xt3, 1);
            if (k == 0)
                k_theta<1><<<ng3, 256, 0, stream>>>(xt3, theta, theta_b, acc3);
            else
                k_theta<0><<<ng3, 256, 0, stream>>>(xt3, theta + 4096, theta_b + 64, acc3);
        }

        k_comb<<<12500, 256, 0, stream>>>(acc3, acc3 + HGF, acc3 + 2 * HGF,
                                          att_m, att, HG, HG16);
        dim3 ah(BB, NH, 2);
        k_attnh<<<ah, 256, 0, stream>>>(HG, input_seq, label_seq, w_hist, w_fut, out, hout);
        dim3 ao(BB, 2);
        k_attno<<<ao, 256, 0, stream>>>(hout, w_hist, w_fut, out, A16);
        dim3 bg(196, 100);
        k_bigmm_mfma<<<bg, 256, 0, stream>>>(A16, HG16, out);
        k_mask<<<BB * LL, 64, 0, stream>>>(input_seq, out);
    } else {
        // fallback: atomic fp32 path; transients in the dead output_past region
        float* HG = ws;
        float* invB = HG + HGF;
        float* invD = invB + 50000;
        if (ws_size < (HGF + 100000 + 64) * 4) {
            HG = out + 36550000u;
            invB = HG + HGF;
            invD = invB + 50000;
        }
        float* trans = out;
        float* acc0 = trans;
        float* acc1 = trans + HGF;
        float* acc2 = trans + 2 * HGF;
        float* cur = trans + 3 * HGF;
        float* xt = trans + 4 * HGF;
        float* m = trans + 5 * HGF;
        float* accs[3] = {acc0, acc1, acc2};
        const int* edges[3] = {eg, ei, eu};
        for (int c = 0; c < 3; c++) {
            const int* node = edges[c];
            const int* hedge = edges[c] + NE;
            k_zero<<<(100000 + 255) / 256, 256, 0, stream>>>(invB, 100000);
            k_deg<<<(NE + 255) / 256, 256, 0, stream>>>(node, hedge, invD, invB);
            k_inv<<<(100000 + 255) / 256, 256, 0, stream>>>(invB, 100000);
            k_gate<<<12500, 256, 0, stream>>>(emb, gate_w + c * 4096, gate_b + c * 64, cur, accs[c]);
            for (int k = 0; k < 2; k++) {
                k_mm64<<<12500, 256, 0, stream>>>(cur, theta + k * 4096, xt);
                k_zero<<<12500, 256, 0, stream>>>(m, (int)HGF);
                k_scat<<<NE / 4, 256, 0, stream>>>(xt, node, hedge, nullptr, m);
                k_zero<<<12500, 256, 0, stream>>>(cur, (int)HGF);
                k_scat<<<NE / 4, 256, 0, stream>>>(m, hedge, node, invB, cur);
                k_fin<<<12500, 256, 0, stream>>>(cur, invD, theta_b + k * 64, accs[c]);
            }
        }
        k_comb<<<12500, 256, 0, stream>>>(acc0, acc1, acc2, att_m, att, HG, (ushortt*)m);
        dim3 ag(BB, 2);
        k_attnF<<<ag, 256, 0, stream>>>(HG, input_seq, label_seq, w_hist, w_fut, out, xt);
        dim3 bg5(196, 4);
        k_bigmm5<<<bg5, 256, 0, stream>>>(xt, HG, out);
        k_mask<<<BB * LL, 64, 0, stream>>>(input_seq, out);
    }
}

// Round 18
// 828.562 us; speedup vs baseline: 1.4337x; 1.4337x over previous
//
#include <hip/hip_runtime.h>
#include <math.h>

#define N_NODE 50000
#define DD 64
#define NE 800000
#define BB 16
#define LL 50
#define NH 8
#define DK 8
#define NEGV -1e9f
#define NB 49      // buckets over segment space, key>>10
#define NBLK 256   // partition blocks
#define EPB 3125   // edges per partition block

// fp32 output layout (element offsets)
#define OFF_PDIST 80000000u
#define OFF_FDIST 80320000u
#define OFF_L2P 80640000u
#define OFF_L2F 80691200u

typedef unsigned short ushortt;
typedef __attribute__((ext_vector_type(8))) short bf16x8v;
typedef __attribute__((ext_vector_type(4))) float f32x4v;

__device__ __forceinline__ float b2f(ushortt h) { return __uint_as_float(((unsigned)h) << 16); }
__device__ __forceinline__ ushortt f2b(float f) {
    unsigned u = __float_as_uint(f);
    return (ushortt)((u + 0x7fffu + ((u >> 16) & 1u)) >> 16);
}
__device__ __forceinline__ void acc8(float* a, uint4 x) {
    a[0] += b2f((ushortt)(x.x)); a[1] += b2f((ushortt)(x.x >> 16));
    a[2] += b2f((ushortt)(x.y)); a[3] += b2f((ushortt)(x.y >> 16));
    a[4] += b2f((ushortt)(x.z)); a[5] += b2f((ushortt)(x.z >> 16));
    a[6] += b2f((ushortt)(x.w)); a[7] += b2f((ushortt)(x.w >> 16));
}
__device__ __forceinline__ uint4 pack8(const float* a) {
    uint4 w;
    w.x = (unsigned)f2b(a[0]) | ((unsigned)f2b(a[1]) << 16);
    w.y = (unsigned)f2b(a[2]) | ((unsigned)f2b(a[3]) << 16);
    w.z = (unsigned)f2b(a[4]) | ((unsigned)f2b(a[5]) << 16);
    w.w = (unsigned)f2b(a[6]) | ((unsigned)f2b(a[7]) << 16);
    return w;
}

// ---------------- zero fill ----------------
__global__ void k_zero(float* p, int n) {
    int i = blockIdx.x * 256 + threadIdx.x;
    if (i < n) p[i] = 0.0f;
}

// ================= CSR build: block-private counting sort =================
__global__ __launch_bounds__(256) void k_cnt(const int* __restrict__ eg,
                                             const int* __restrict__ ei,
                                             const int* __restrict__ eu,
                                             int* __restrict__ hist) {
    int c = blockIdx.y;
    const int* ed = (c == 0) ? eg : ((c == 1) ? ei : eu);
    int blk = blockIdx.x;
    __shared__ int lc[2 * NB];
    int tid = threadIdx.x;
    for (int j = tid; j < 2 * NB; j += 256) lc[j] = 0;
    __syncthreads();
    int e0 = blk * EPB;
    for (int i = e0 + tid; i < e0 + EPB; i += 256) {
        atomicAdd(&lc[ed[NE + i] >> 10], 1);
        atomicAdd(&lc[NB + (ed[i] >> 10)], 1);
    }
    __syncthreads();
    for (int j = tid; j < 2 * NB; j += 256) {
        int side = (j >= NB);
        int b = side ? (j - NB) : j;
        hist[(((side * 3 + c) * NB) + b) * NBLK + blk] = lc[j];
    }
}

__global__ __launch_bounds__(256) void k_scanH(int* __restrict__ hist, int* __restrict__ bb) {
    int t6 = blockIdx.x;
    int* h = hist + t6 * NB * NBLK;
    __shared__ int part[256];
    int tid = threadIdx.x;
    const int CH = (NB * NBLK) / 256;  // 49
    int base = tid * CH;
    int s = 0;
    for (int i = 0; i < CH; i++) s += h[base + i];
    part[tid] = s;
    __syncthreads();
    for (int o = 1; o < 256; o <<= 1) {
        int v = (tid >= o) ? part[tid - o] : 0;
        __syncthreads();
        part[tid] += v;
        __syncthreads();
    }
    int run = (tid == 0) ? 0 : part[tid - 1];
    for (int i = 0; i < CH; i++) {
        int idx = base + i;
        int v = h[idx];
        if ((idx & (NBLK - 1)) == 0) bb[t6 * (NB + 1) + (idx >> 8)] = run;
        h[idx] = run;
        run += v;
    }
    if (tid == 255) bb[t6 * (NB + 1) + NB] = run;
}

__global__ __launch_bounds__(256) void k_part2(const int* __restrict__ eg,
                                               const int* __restrict__ ei,
                                               const int* __restrict__ eu,
                                               const int* __restrict__ hist,
                                               unsigned* __restrict__ poolB,
                                               unsigned* __restrict__ poolD) {
    int c = blockIdx.y;
    const int* ed = (c == 0) ? eg : ((c == 1) ? ei : eu);
    int blk = blockIdx.x;
    __shared__ int curB[NB], curD[NB];
    int tid = threadIdx.x;
    for (int j = tid; j < NB; j += 256) {
        curB[j] = hist[(((0 * 3 + c) * NB) + j) * NBLK + blk];
        curD[j] = hist[(((1 * 3 + c) * NB) + j) * NBLK + blk];
    }
    __syncthreads();
    unsigned* pB = poolB + c * 800000;
    unsigned* pD = poolD + c * 800000;
    int e0 = blk * EPB;
    for (int i = e0 + tid; i < e0 + EPB; i += 256) {
        int n = ed[i], h = ed[NE + i];
        int pb = atomicAdd(&curB[h >> 10], 1);
        pB[pb] = ((unsigned)h << 16) | (unsigned)n;
        int pd = atomicAdd(&curD[n >> 10], 1);
        pD[pd] = ((unsigned)n << 16) | (unsigned)h;
    }
}

__global__ __launch_bounds__(256) void k_bucket(const unsigned* __restrict__ poolB,
                                                const unsigned* __restrict__ poolD,
                                                const int* __restrict__ bb,
                                                int* __restrict__ nbrB3, int* __restrict__ nbrD3,
                                                int* __restrict__ offB3, int* __restrict__ offD3,
                                                float* __restrict__ invB3, float* __restrict__ invD3) {
    int b = blockIdx.x, c = blockIdx.y, side = blockIdx.z;
    const unsigned* pool = (side ? poolD : poolB) + c * 800000;
    int* nbr = (side ? nbrD3 : nbrB3) + c * 800000;
    int* off = (side ? offD3 : offB3) + c * 50001;
    float* inv = (side ? invD3 : invB3) + c * 50000;
    int t6 = side * 3 + c;
    int s0 = bb[t6 * (NB + 1) + b], s1 = bb[t6 * (NB + 1) + b + 1];
    int baseSeg = b << 10;
    __shared__ int cnt[1024];
    __shared__ int ofs[1024];
    __shared__ int part[256];
    int tid = threadIdx.x;
    for (int j = tid; j < 1024; j += 256) cnt[j] = 0;
    __syncthreads();
    for (int i = s0 + tid; i < s1; i += 256)
        atomicAdd(&cnt[(pool[i] >> 16) & 1023], 1);
    __syncthreads();
    int t4 = tid * 4;
    int a0 = cnt[t4], a1 = cnt[t4 + 1], a2 = cnt[t4 + 2], a3 = cnt[t4 + 3];
    part[tid] = a0 + a1 + a2 + a3;
    __syncthreads();
    for (int o = 1; o < 256; o <<= 1) {
        int v = (tid >= o) ? part[tid - o] : 0;
        __syncthreads();
        part[tid] += v;
        __syncthreads();
    }
    int excl = (tid == 0) ? 0 : part[tid - 1];
    ofs[t4] = excl;
    ofs[t4 + 1] = excl + a0;
    ofs[t4 + 2] = excl + a0 + a1;
    ofs[t4 + 3] = excl + a0 + a1 + a2;
    __syncthreads();
    for (int ls = tid; ls < 1024; ls += 256) {
        int seg = baseSeg + ls;
        if (seg < N_NODE) {
            off[seg] = s0 + ofs[ls];
            inv[seg] = cnt[ls] ? 1.0f / (float)cnt[ls] : 0.0f;
        }
    }
    if (b == NB - 1 && tid == 0) off[N_NODE] = NE;
    __syncthreads();
    for (int i = s0 + tid; i < s1; i += 256) {
        unsigned u = pool[i];
        int ls = (u >> 16) & 1023;
        int p = atomicAdd(&ofs[ls], 1);
        nbr[s0 + p] = (int)(u & 0xFFFFu);
    }
}

// ---------------- fused gate ----------------
__global__ __launch_bounds__(256) void k_gateX(const float* __restrict__ emb,
                                               const float* __restrict__ gate_w,
                                               const float* __restrict__ gate_b,
                                               float* __restrict__ acc3,
                                               ushortt* __restrict__ xt3) {
    int c = blockIdx.y;
    const float* W = gate_w + c * 4096;
    const float* bias = gate_b + c * 64;
    float* acc = acc3 + (size_t)c * 3200000;
    ushortt* xt = xt3 + (size_t)c * 3200000;
    __shared__ float sW[64 * 64];
    __shared__ float sx[4][64];
    int tid = threadIdx.x;
    for (int i = tid; i < 4096; i += 256) sW[i] = W[i];
    int r = tid >> 6;
    int d = tid & 63;
    int n = blockIdx.x * 4 + r;
    sx[r][d] = emb[n * DD + d];
    __syncthreads();
    float a = bias[d];
#pragma unroll
    for (int k = 0; k < 64; k++) a += sx[r][k] * sW[k * 64 + d];
    float x = sx[r][d] * (1.0f / (1.0f + expf(-a)));
    acc[n * DD + d] = x;
    xt[n * DD + d] = f2b(x);
}

// ---------------- hyperedge gather (bf16 in/out), prefetched ----------------
__global__ __launch_bounds__(256) void k_gathB3(const ushortt* __restrict__ xt3,
                                                const int* __restrict__ offB3,
                                                const int* __restrict__ nbrB3,
                                                const float* __restrict__ invB3,
                                                ushortt* __restrict__ m3) {
    int c = blockIdx.y;
    const ushortt* src = xt3 + (size_t)c * 3200000;
    const int* off = offB3 + c * 50001;
    const int* nbr = nbrB3 + c * 800000;
    const float* invSeg = invB3 + c * 50000;
    ushortt* dst = m3 + (size_t)c * 3200000;
    int seg = blockIdx.x * 4 + (threadIdx.x >> 6);
    int lane = threadIdx.x & 63;
    int sub = lane >> 3;
    int c8 = lane & 7;
    int s = off[seg], e = off[seg + 1];
    float a[8] = {0.f, 0.f, 0.f, 0.f, 0.f, 0.f, 0.f, 0.f};
    int i = s + sub;
    if (i < e) {
        uint4 x = ((const uint4*)(src + (size_t)nbr[i] * DD))[c8];
        for (i += 8; i < e; i += 8) {
            uint4 nx = ((const uint4*)(src + (size_t)nbr[i] * DD))[c8];
            acc8(a, x);
            x = nx;
        }
        acc8(a, x);
    }
#pragma unroll
    for (int j = 0; j < 8; j++) {
        a[j] += __shfl_xor(a[j], 8, 64);
        a[j] += __shfl_xor(a[j], 16, 64);
        a[j] += __shfl_xor(a[j], 32, 64);
    }
    if (sub == 0) {
        float sc = invSeg[seg];
        float b[8];
#pragma unroll
        for (int j = 0; j < 8; j++) b[j] = a[j] * sc;
        ((uint4*)(dst + (size_t)seg * DD))[c8] = pack8(b);
    }
}

// ---------------- node gather + theta + finalize, prefetched ----------------
template <int WRITE_XT>
__global__ __launch_bounds__(256) void k_gathD3f(const ushortt* __restrict__ m3,
                                                 const int* __restrict__ offD3,
                                                 const int* __restrict__ nbrD3,
                                                 const float* __restrict__ invD3,
                                                 const float* __restrict__ theta,
                                                 const float* __restrict__ theta_b,
                                                 float* __restrict__ acc3,
                                                 ushortt* __restrict__ xt3) {
    int c = blockIdx.y;
    const ushortt* m = m3 + (size_t)c * 3200000;
    const int* off = offD3 + c * 50001;
    const int* nbr = nbrD3 + c * 800000;
    const float* invD = invD3 + c * 50000;
    float* acc = acc3 + (size_t)c * 3200000;
    ushortt* xt = xt3 + (size_t)c * 3200000;

    __shared__ float sTh[64 * 64];
    __shared__ float sx[4][64];
    __shared__ float sb[64];
    int tid = threadIdx.x;
    for (int i = tid; i < 4096; i += 256) sTh[i] = theta[i];
    if (tid < 64) sb[tid] = theta_b[tid];

    int w = tid >> 6;
    int seg = blockIdx.x * 4 + w;
    int lane = tid & 63;
    int sub = lane >> 3;
    int c8 = lane & 7;
    int s = off[seg], e = off[seg + 1];
    float a[8] = {0.f, 0.f, 0.f, 0.f, 0.f, 0.f, 0.f, 0.f};
    int i = s + sub;
    if (i < e) {
        uint4 x = ((const uint4*)(m + (size_t)nbr[i] * DD))[c8];
        for (i += 8; i < e; i += 8) {
            uint4 nx = ((const uint4*)(m + (size_t)nbr[i] * DD))[c8];
            acc8(a, x);
            x = nx;
        }
        acc8(a, x);
    }
#pragma unroll
    for (int j = 0; j < 8; j++) {
        a[j] += __shfl_xor(a[j], 8, 64);
        a[j] += __shfl_xor(a[j], 16, 64);
        a[j] += __shfl_xor(a[j], 32, 64);
    }
    if (sub == 0) {
        float iD = invD[seg];
#pragma unroll
        for (int j = 0; j < 8; j++) sx[w][c8 * 8 + j] = a[j] * iD;
    }
    __syncthreads();

    int d = lane;
    float v = sb[d];
#pragma unroll
    for (int k = 0; k < 64; k++) v += sx[w][k] * sTh[k * 64 + d];
    float ss = v * v;
#pragma unroll
    for (int o = 32; o; o >>= 1) ss += __shfl_xor(ss, o, 64);
    float nr = fmaxf(sqrtf(ss), 1e-12f);
    size_t idx = (size_t)seg * DD + d;
    acc[idx] += v / nr;
    if (WRITE_XT) xt[idx] = f2b(v);
}

// ---------------- channel softmax combine -> HG (fp32 + bf16) ----------------
__global__ __launch_bounds__(256) void k_comb(const float* __restrict__ a0,
                                              const float* __restrict__ a1,
                                              const float* __restrict__ a2,
                                              const float* __restrict__ att_m,
                                              const float* __restrict__ att,
                                              float* __restrict__ HG,
                                              ushortt* __restrict__ HG16) {
    __shared__ float svv[64];
    int tid = threadIdx.x;
    if (tid < 64) {
        float s = 0.f;
        for (int k = 0; k < 64; k++) s += att_m[tid * 64 + k] * att[k];
        svv[tid] = s;
    }
    __syncthreads();
    int r = tid >> 6;
    int d = tid & 63;
    int n = blockIdx.x * 4 + r;
    float x0 = a0[n * DD + d], x1 = a1[n * DD + d], x2 = a2[n * DD + d];
    float vd = svv[d];
    float l0 = x0 * vd, l1 = x1 * vd, l2 = x2 * vd;
#pragma unroll
    for (int o = 32; o; o >>= 1) {
        l0 += __shfl_xor(l0, o, 64);
        l1 += __shfl_xor(l1, o, 64);
        l2 += __shfl_xor(l2, o, 64);
    }
    l0 *= (1.0f / 3.0f); l1 *= (1.0f / 3.0f); l2 *= (1.0f / 3.0f);
    float mx = fmaxf(l0, fmaxf(l1, l2));
    float e0 = expf(l0 - mx), e1 = expf(l1 - mx), e2 = expf(l2 - mx);
    float inv = 1.0f / (e0 + e1 + e2);
    float hv = (e0 * x0 + e1 * x1 + e2 * x2) * inv * (1.0f / 3.0f);
    HG[n * DD + d] = hv;
    HG16[n * DD + d] = f2b(hv);
}

// ---------------- attention + fused l2norm; wave-parallel softmax ----------------
__global__ __launch_bounds__(256) void k_attn(const float* __restrict__ HG,
                                              const int* __restrict__ iseq,
                                              const int* __restrict__ lseq,
                                              const float* __restrict__ w_hist,
                                              const float* __restrict__ w_fut,
                                              float* __restrict__ dout,
                                              ushortt* __restrict__ attout16,
                                              float* __restrict__ attoutF) {
    int b = blockIdx.x;
    int dir = blockIdx.y;
    const int* seq = (dir == 0) ? iseq : lseq;
    const float* W = (dir == 0) ? w_hist : w_fut;
    float* dist = dout + ((dir == 0) ? OFF_PDIST : OFF_FDIST);

    __shared__ float sX[LL * 64];
    __shared__ float sQ[LL * 64];
    __shared__ float sK[LL * 64];
    __shared__ float sV[LL * 64];
    __shared__ float sS[LL * LL];
    __shared__ float sInv[64];
    __shared__ int sseq[LL];

    int tid = threadIdx.x;
    int w = tid >> 6;
    int lane = tid & 63;
    if (tid < LL) sseq[tid] = seq[b * LL + tid];
    __syncthreads();
    for (int idx = tid; idx < LL * 64; idx += 256) {
        int i = idx >> 6, d = idx & 63;
        sX[idx] = HG[sseq[i] * DD + d];
    }
    __syncthreads();
    for (int idx = tid; idx < LL * 64; idx += 256) {
        int i = idx >> 6, d = idx & 63;
        float q = 0, k = 0, v = 0;
        for (int kk = 0; kk < 64; kk++) {
            float x = sX[i * 64 + kk];
            q += x * W[kk * 64 + d];
            k += x * W[4096 + kk * 64 + d];
            v += x * W[8192 + kk * 64 + d];
        }
        sQ[idx] = q; sK[idx] = k; sV[idx] = v;
    }
    __syncthreads();
    for (int idx = tid; idx < LL * 64; idx += 256) sX[idx] = 0.0f;
    __syncthreads();

    const float scale = 0.35355339059327373f;  // 1/sqrt(8)
    for (int h = 0; h < NH; h++) {
        for (int idx = tid; idx < LL * LL; idx += 256) {
            int i = idx / LL, j = idx % LL;
            float s = 0;
#pragma unroll
            for (int d = 0; d < DK; d++) s += sQ[i * 64 + h * 8 + d] * sK[j * 64 + h * 8 + d];
            s *= scale;
            bool allowed = (dir == 0) ? (j <= i) : (j >= i);
            if (!allowed) s = NEGV;
            if (sseq[j] == 0) s = NEGV;
            sS[idx] = s;
        }
        __syncthreads();
        // wave-parallel softmax: wave w handles rows w, w+4, ...; lanes parallel over cols
        for (int i = w; i < LL; i += 4) {
            float v = (lane < LL) ? sS[i * LL + lane] : -INFINITY;
            float mx = v;
#pragma unroll
            for (int o = 32; o; o >>= 1) mx = fmaxf(mx, __shfl_xor(mx, o, 64));
            float e = (lane < LL) ? expf(v - mx) : 0.0f;
            float sum = e;
#pragma unroll
            for (int o = 32; o; o >>= 1) sum += __shfl_xor(sum, o, 64);
            float p = e / sum;
            if (lane < LL) {
                sS[i * LL + lane] = p;
                dist[((b * NH + h) * LL + i) * LL + lane] = p;
            }
        }
        __syncthreads();
        for (int idx = tid; idx < LL * DK; idx += 256) {
            int i = idx / DK, d8 = idx % DK;
            float o = 0;
            for (int j = 0; j < LL; j++) o += sS[i * LL + j] * sV[j * 64 + h * 8 + d8];
            sX[i * 64 + h * 8 + d8] = o;
        }
        __syncthreads();
    }
    // output projection into sQ (reuse)
    for (int idx = tid; idx < LL * 64; idx += 256) {
        int i = idx >> 6, d = idx & 63;
        float o = 0;
        for (int kk = 0; kk < 64; kk++) o += sX[i * 64 + kk] * W[3 * 4096 + kk * 64 + d];
        sQ[idx] = o;
        int row = dir * 800 + b * LL + i;
        attout16[row * 64 + d] = f2b(o);
        if (attoutF) attoutF[row * 64 + d] = o;
    }
    __syncthreads();
    if (tid < 64) {
        float s = 0;
        for (int l = 0; l < LL; l++) {
            float x = sQ[l * 64 + tid];
            s += x * x;
        }
        sInv[tid] = 1.0f / fmaxf(sqrtf(s), 1e-12f);
    }
    __syncthreads();
    float* ol2 = dout + ((dir == 0) ? OFF_L2P : OFF_L2F) + b * LL * 64;
    for (int idx = tid; idx < LL * 64; idx += 256) {
        int d = idx & 63;
        ol2[idx] = sQ[idx] * sInv[d];
    }
}

// ---------------- big matmul via MFMA; LDS-transposed contiguous nt stores ----------------
// grid (196, 100): block = 16 rows x 256 cols.
__global__ __launch_bounds__(256) void k_bigmm_mfma(const ushortt* __restrict__ A16,
                                                    const ushortt* __restrict__ HG16,
                                                    float* __restrict__ out) {
    __shared__ float sO[16][260];
    int tid = threadIdx.x;
    int lane = tid & 63;
    int w = tid >> 6;
    int rt = blockIdx.y;
    int colBase = blockIdx.x * 256;
    int lrow = lane & 15;
    int kb = (lane >> 4) * 8;
    int arow = rt * 16 + lrow;
    bf16x8v a0 = *(const bf16x8v*)(A16 + (size_t)arow * 64 + kb);
    bf16x8v a1 = *(const bf16x8v*)(A16 + (size_t)arow * 64 + kb + 32);
#pragma unroll
    for (int ct = 0; ct < 4; ct++) {
        int lc = w * 64 + ct * 16 + lrow;
        int col = colBase + lc;
        int colc = (col < N_NODE) ? col : 0;
        bf16x8v b0 = *(const bf16x8v*)(HG16 + (size_t)colc * 64 + kb);
        bf16x8v b1 = *(const bf16x8v*)(HG16 + (size_t)colc * 64 + kb + 32);
        f32x4v acc = {0.f, 0.f, 0.f, 0.f};
        acc = __builtin_amdgcn_mfma_f32_16x16x32_bf16(a0, b0, acc, 0, 0, 0);
        acc = __builtin_amdgcn_mfma_f32_16x16x32_bf16(a1, b1, acc, 0, 0, 0);
        int r0 = (lane >> 4) * 4;
#pragma unroll
        for (int j = 0; j < 4; j++) sO[r0 + j][lc] = acc[j];
    }
    __syncthreads();
#pragma unroll
    for (int j = 0; j < 4; j++) {
        int r = w * 4 + j;
        int row = rt * 16 + r;
        int c0 = colBase + lane * 4;
        f32x4v v = {sO[r][lane * 4], sO[r][lane * 4 + 1],
                    sO[r][lane * 4 + 2], sO[r][lane * 4 + 3]};
        if (c0 + 3 < N_NODE) {
            __builtin_nontemporal_store(v, (f32x4v*)(out + (size_t)row * 50000 + c0));
        } else {
            for (int t = 0; t < 4; t++)
                if (c0 + t < N_NODE) out[(size_t)row * 50000 + c0 + t] = v[t];
        }
    }
}

// ---------------- prev-user mask ----------------
__global__ __launch_bounds__(64) void k_mask(const int* __restrict__ iseq,
                                             float* __restrict__ out) {
    int row = blockIdx.x;
    int b = row / LL, i = row % LL;
    __shared__ int s[LL];
    int tid = threadIdx.x;
    if (tid < LL) s[tid] = iseq[b * LL + tid];
    __syncthreads();
    float* o = out + (size_t)row * 50000;
    if (tid == 0) o[0] -= 1000.0f;
    if (tid < LL && tid <= i) {
        int c = s[tid];
        if (c > 0 && c < N_NODE) {
            bool first = true;
            for (int j = 0; j < tid; j++)
                if (s[j] == c) { first = false; break; }
            if (first) o[c] -= 1000.0f;
        }
    }
}

// ================= fallback atomic path kernels =================
__global__ void k_deg(const int* __restrict__ node, const int* __restrict__ hedge,
                      float* __restrict__ Ddeg, float* __restrict__ Bdeg) {
    int e = blockIdx.x * 256 + threadIdx.x;
    if (e < NE) {
        atomicAdd(&Ddeg[node[e]], 1.0f);
        atomicAdd(&Bdeg[hedge[e]], 1.0f);
    }
}

__global__ void k_inv(float* a, int n) {
    int i = blockIdx.x * 256 + threadIdx.x;
    if (i < n) a[i] = (a[i] > 0.0f) ? (1.0f / a[i]) : 0.0f;
}

__global__ __launch_bounds__(256) void k_scat(const float* __restrict__ src,
                                              const int* __restrict__ gidx,
                                              const int* __restrict__ sidx,
                                              const float* __restrict__ scale,
                                              float* __restrict__ dst) {
    int e = blockIdx.x * 4 + (threadIdx.x >> 6);
    int d = threadIdx.x & 63;
    if (e >= NE) return;
    int g = gidx[e];
    int s = sidx[e];
    float v = src[g * DD + d];
    if (scale) v *= scale[g];
    atomicAdd(&dst[s * DD + d], v);
}

__global__ __launch_bounds__(256) void k_fin(float* __restrict__ cur,
                                             const float* __restrict__ invD,
                                             const float* __restrict__ bias,
                                             float* __restrict__ acc) {
    int r = threadIdx.x >> 6;
    int d = threadIdx.x & 63;
    int n = blockIdx.x * 4 + r;
    float v = cur[n * DD + d] * invD[n] + bias[d];
    cur[n * DD + d] = v;
    float s = v * v;
#pragma unroll
    for (int o = 32; o; o >>= 1) s += __shfl_xor(s, o, 64);
    float nr = fmaxf(sqrtf(s), 1e-12f);
    acc[n * DD + d] += v / nr;
}

__global__ __launch_bounds__(256) void k_gate(const float* __restrict__ emb,
                                              const float* __restrict__ W,
                                              const float* __restrict__ bias,
                                              float* __restrict__ cur,
                                              float* __restrict__ acc) {
    __shared__ float sW[64 * 64];
    __shared__ float sx[4][64];
    int tid = threadIdx.x;
    for (int i = tid; i < 4096; i += 256) sW[i] = W[i];
    int r = tid >> 6;
    int d = tid & 63;
    int n = blockIdx.x * 4 + r;
    sx[r][d] = emb[n * DD + d];
    __syncthreads();
    float a = bias[d];
#pragma unroll
    for (int k = 0; k < 64; k++) a += sx[r][k] * sW[k * 64 + d];
    float x = sx[r][d] * (1.0f / (1.0f + expf(-a)));
    cur[n * DD + d] = x;
    acc[n * DD + d] = x;
}

__global__ __launch_bounds__(256) void k_mm64(const float* __restrict__ X,
                                              const float* __restrict__ W,
                                              float* __restrict__ Y) {
    __shared__ float sW[64 * 64];
    __shared__ float sx[4][64];
    int tid = threadIdx.x;
    for (int i = tid; i < 4096; i += 256) sW[i] = W[i];
    int r = tid >> 6;
    int d = tid & 63;
    int n = blockIdx.x * 4 + r;
    sx[r][d] = X[n * DD + d];
    __syncthreads();
    float a = 0.0f;
#pragma unroll
    for (int k = 0; k < 64; k++) a += sx[r][k] * sW[k * 64 + d];
    Y[n * DD + d] = a;
}

__global__ __launch_bounds__(256) void k_attnF(const float* __restrict__ HG,
                                               const int* __restrict__ iseq,
                                               const int* __restrict__ lseq,
                                               const float* __restrict__ w_hist,
                                               const float* __restrict__ w_fut,
                                               float* __restrict__ dout,
                                               float* __restrict__ attoutF) {
    int b = blockIdx.x;
    int dir = blockIdx.y;
    const int* seq = (dir == 0) ? iseq : lseq;
    const float* W = (dir == 0) ? w_hist : w_fut;
    float* dist = dout + ((dir == 0) ? OFF_PDIST : OFF_FDIST);
    __shared__ float sX[LL * 64];
    __shared__ float sQ[LL * 64];
    __shared__ float sK[LL * 64];
    __shared__ float sV[LL * 64];
    __shared__ float sS[LL * LL];
    __shared__ float sInv[64];
    __shared__ int sseq[LL];
    int tid = threadIdx.x;
    int w = tid >> 6, lane = tid & 63;
    if (tid < LL) sseq[tid] = seq[b * LL + tid];
    __syncthreads();
    for (int idx = tid; idx < LL * 64; idx += 256) {
        int i = idx >> 6, d = idx & 63;
        sX[idx] = HG[sseq[i] * DD + d];
    }
    __syncthreads();
    for (int idx = tid; idx < LL * 64; idx += 256) {
        int i = idx >> 6, d = idx & 63;
        float q = 0, k = 0, v = 0;
        for (int kk = 0; kk < 64; kk++) {
            float x = sX[i * 64 + kk];
            q += x * W[kk * 64 + d];
            k += x * W[4096 + kk * 64 + d];
            v += x * W[8192 + kk * 64 + d];
        }
        sQ[idx] = q; sK[idx] = k; sV[idx] = v;
    }
    __syncthreads();
    for (int idx = tid; idx < LL * 64; idx += 256) sX[idx] = 0.0f;
    __syncthreads();
    const float scale = 0.35355339059327373f;
    for (int h = 0; h < NH; h++) {
        for (int idx = tid; idx < LL * LL; idx += 256) {
            int i = idx / LL, j = idx % LL;
            float s = 0;
#pragma unroll
            for (int d = 0; d < DK; d++) s += sQ[i * 64 + h * 8 + d] * sK[j * 64 + h * 8 + d];
            s *= scale;
            bool allowed = (dir == 0) ? (j <= i) : (j >= i);
            if (!allowed || sseq[j] == 0) s = NEGV;
            sS[idx] = s;
        }
        __syncthreads();
        for (int i = w; i < LL; i += 4) {
            float v = (lane < LL) ? sS[i * LL + lane] : -INFINITY;
            float mx = v;
#pragma unroll
            for (int o = 32; o; o >>= 1) mx = fmaxf(mx, __shfl_xor(mx, o, 64));
            float e = (lane < LL) ? expf(v - mx) : 0.0f;
            float sum = e;
#pragma unroll
            for (int o = 32; o; o >>= 1) sum += __shfl_xor(sum, o, 64);
            float p = e / sum;
            if (lane < LL) {
                sS[i * LL + lane] = p;
                dist[((b * NH + h) * LL + i) * LL + lane] = p;
            }
        }
        __syncthreads();
        for (int idx = tid; idx < LL * DK; idx += 256) {
            int i = idx / DK, d8 = idx % DK;
            float o = 0;
            for (int j = 0; j < LL; j++) o += sS[i * LL + j] * sV[j * 64 + h * 8 + d8];
            sX[i * 64 + h * 8 + d8] = o;
        }
        __syncthreads();
    }
    for (int idx = tid; idx < LL * 64; idx += 256) {
        int i = idx >> 6, d = idx & 63;
        float o = 0;
        for (int kk = 0; kk < 64; kk++) o += sX[i * 64 + kk] * W[3 * 4096 + kk * 64 + d];
        sQ[idx] = o;
        attoutF[(dir * 800 + b * LL + i) * 64 + d] = o;
    }
    __syncthreads();
    if (tid < 64) {
        float s = 0;
        for (int l = 0; l < LL; l++) {
            float x = sQ[l * 64 + tid];
            s += x * x;
        }
        sInv[tid] = 1.0f / fmaxf(sqrtf(s), 1e-12f);
    }
    __syncthreads();
    float* ol2 = dout + ((dir == 0) ? OFF_L2P : OFF_L2F) + b * LL * 64;
    for (int idx = tid; idx < LL * 64; idx += 256) {
        int d = idx & 63;
        ol2[idx] = sQ[idx] * sInv[d];
    }
}

__global__ __launch_bounds__(256) void k_bigmm5(const float* __restrict__ A,
                                                const float* __restrict__ HG,
                                                float* __restrict__ out) {
    int col = blockIdx.x * 256 + threadIdx.x;
    int r0 = blockIdx.y * 400;
    bool ok = (col < N_NODE);
    float4 h[16];
    const float4* hp = (const float4*)(HG + (size_t)(ok ? col : 0) * 64);
#pragma unroll
    for (int t = 0; t < 16; t++) h[t] = hp[t];
    if (!ok) return;
    for (int r = 0; r < 400; r++) {
        int row = r0 + r;
        const float* ar = A + (size_t)row * 64;
        float q0 = 0.f, q1 = 0.f, q2 = 0.f, q3 = 0.f;
#pragma unroll
        for (int t = 0; t < 16; t++) {
            q0 += ar[4 * t + 0] * h[t].x;
            q1 += ar[4 * t + 1] * h[t].y;
            q2 += ar[4 * t + 2] * h[t].z;
            q3 += ar[4 * t + 3] * h[t].w;
        }
        out[(size_t)row * 50000 + col] = (q0 + q1) + (q2 + q3);
    }
}

extern "C" void kernel_launch(void* const* d_in, const int* in_sizes, int n_in,
                              void* d_out, int out_size, void* d_ws, size_t ws_size,
                              hipStream_t stream) {
    const int* input_seq = (const int*)d_in[0];
    const int* label_seq = (const int*)d_in[1];
    const int* eg = (const int*)d_in[4];
    const int* ei = (const int*)d_in[5];
    const int* eu = (const int*)d_in[6];
    const float* emb = (const float*)d_in[7];
    const float* gate_w = (const float*)d_in[8];
    const float* gate_b = (const float*)d_in[9];
    const float* att = (const float*)d_in[10];
    const float* att_m = (const float*)d_in[11];
    const float* theta = (const float*)d_in[12];
    const float* theta_b = (const float*)d_in[13];
    const float* w_hist = (const float*)d_in[14];
    const float* w_fut = (const float*)d_in[15];

    float* out = (float*)d_out;
    float* ws = (float*)d_ws;

    const size_t HGF = 3200000;
    const int HISTN = 6 * NB * NBLK;  // 75264
    const size_t needA = (HGF + 150000 + 150000 +
                          (size_t)(HISTN + 6 * (NB + 1) + 64) +
                          300006 + 4 * 2400000 +
                          2 * 2400000 +
                          3 * HGF +
                          HGF / 2 + 51200 + 1024) * 4;

    if (ws_size >= needA) {
        size_t o = 0;
        float* HG = ws + o; o += HGF;
        float* invB3 = ws + o; o += 150000;
        float* invD3 = ws + o; o += 150000;
        int* hist = (int*)(ws + o); o += HISTN;
        int* bbarr = (int*)(ws + o); o += 6 * (NB + 1) + 64;
        int* offB3 = (int*)(ws + o); o += 150003;
        int* offD3 = (int*)(ws + o); o += 150003 + 2;
        int* nbrB3 = (int*)(ws + o); o += 2400000;
        int* nbrD3 = (int*)(ws + o); o += 2400000;
        unsigned* poolB = (unsigned*)(ws + o); o += 2400000;
        unsigned* poolD = (unsigned*)(ws + o); o += 2400000;
        ushortt* xt3 = (ushortt*)(ws + o); o += 4800000;
        ushortt* m3 = (ushortt*)(ws + o); o += 4800000;
        float* acc3 = ws + o; o += 3 * HGF;
        ushortt* HG16 = (ushortt*)(ws + o); o += HGF / 2;
        ushortt* A16 = (ushortt*)(ws + o); o += 51200;

        // CSR build
        dim3 pg(NBLK, 3);
        k_cnt<<<pg, 256, 0, stream>>>(eg, ei, eu, hist);
        k_scanH<<<6, 256, 0, stream>>>(hist, bbarr);
        k_part2<<<pg, 256, 0, stream>>>(eg, ei, eu, hist, poolB, poolD);
        dim3 dg(NB, 3, 2);
        k_bucket<<<dg, 256, 0, stream>>>(poolB, poolD, bbarr, nbrB3, nbrD3,
                                         offB3, offD3, invB3, invD3);

        // HG pipeline (theta post-gather)
        dim3 ng3(12500, 3);
        k_gateX<<<ng3, 256, 0, stream>>>(emb, gate_w, gate_b, acc3, xt3);
        k_gathB3<<<ng3, 256, 0, stream>>>(xt3, offB3, nbrB3, invB3, m3);
        k_gathD3f<1><<<ng3, 256, 0, stream>>>(m3, offD3, nbrD3, invD3,
                                              theta, theta_b, acc3, xt3);
        k_gathB3<<<ng3, 256, 0, stream>>>(xt3, offB3, nbrB3, invB3, m3);
        k_gathD3f<0><<<ng3, 256, 0, stream>>>(m3, offD3, nbrD3, invD3,
                                              theta + 4096, theta_b + 64, acc3, xt3);

        k_comb<<<12500, 256, 0, stream>>>(acc3, acc3 + HGF, acc3 + 2 * HGF,
                                          att_m, att, HG, HG16);
        dim3 ag(BB, 2);
        k_attn<<<ag, 256, 0, stream>>>(HG, input_seq, label_seq, w_hist, w_fut,
                                       out, A16, nullptr);
        dim3 bg(196, 100);
        k_bigmm_mfma<<<bg, 256, 0, stream>>>(A16, HG16, out);
        k_mask<<<BB * LL, 64, 0, stream>>>(input_seq, out);
    } else {
        // fallback: atomic fp32 path; transients in the dead output_past region
        float* HG = ws;
        float* invB = HG + HGF;
        float* invD = invB + 50000;
        if (ws_size < (HGF + 100000 + 64) * 4) {
            HG = out + 36550000u;
            invB = HG + HGF;
            invD = invB + 50000;
        }
        float* trans = out;
        float* acc0 = trans;
        float* acc1 = trans + HGF;
        float* acc2 = trans + 2 * HGF;
        float* cur = trans + 3 * HGF;
        float* xt = trans + 4 * HGF;
        float* m = trans + 5 * HGF;
        float* accs[3] = {acc0, acc1, acc2};
        const int* edges[3] = {eg, ei, eu};
        for (int c = 0; c < 3; c++) {
            const int* node = edges[c];
            const int* hedge = edges[c] + NE;
            k_zero<<<(100000 + 255) / 256, 256, 0, stream>>>(invB, 100000);
            k_deg<<<(NE + 255) / 256, 256, 0, stream>>>(node, hedge, invD, invB);
            k_inv<<<(100000 + 255) / 256, 256, 0, stream>>>(invB, 100000);
            k_gate<<<12500, 256, 0, stream>>>(emb, gate_w + c * 4096, gate_b + c * 64, cur, accs[c]);
            for (int k = 0; k < 2; k++) {
                k_mm64<<<12500, 256, 0, stream>>>(cur, theta + k * 4096, xt);
                k_zero<<<12500, 256, 0, stream>>>(m, (int)HGF);
                k_scat<<<NE / 4, 256, 0, stream>>>(xt, node, hedge, nullptr, m);
                k_zero<<<12500, 256, 0, stream>>>(cur, (int)HGF);
                k_scat<<<NE / 4, 256, 0, stream>>>(m, hedge, node, invB, cur);
                k_fin<<<12500, 256, 0, stream>>>(cur, invD, theta_b + k * 64, accs[c]);
            }
        }
        k_comb<<<12500, 256, 0, stream>>>(acc0, acc1, acc2, att_m, att, HG, (ushortt*)m);
        dim3 ag(BB, 2);
        k_attnF<<<ag, 256, 0, stream>>>(HG, input_seq, label_seq, w_hist, w_fut, out, xt);
        dim3 bg5(196, 4);
        k_bigmm5<<<bg5, 256, 0, stream>>>(xt, HG, out);
        k_mask<<<BB * LL, 64, 0, stream>>>(input_seq, out);
    }
}